// Round 5
// baseline (51.334 us; speedup 1.0000x reference)
//
#include <hip/hip_runtime.h>

// SPD 2x2 matrix-log (closed form) + Linear(3,17), fused.
// R5: direct-store variant. One thread per OUTPUT float4 (4 per thread).
//     Each thread recomputes the 1-2 matrix-logs its floats need (fast-math
//     intrinsics), reads W/b from a small LDS table, stores directly.
//     No LDS staging of outputs, no barrier between compute and store.
//
// For symmetric 2x2 X = [[a,b],[b,c]]:
//   m=(a+c)/2, h=(a-c)/2, disc=sqrt(h^2+b^2), lam1=m+disc, lam2=det/lam1
//   log(X) = p*I + rho*(X - m*I); p=(l1+l2)/2, rho=(l1-l2)/(2*disc)
// vec = [L00, sqrt2*L01, L11]; out = vec @ W^T + b.

#define SQRT2F 1.41421356237309504880f
#define NMAT   2097152

typedef float vfloat4 __attribute__((ext_vector_type(4)));

__device__ __forceinline__ void mat_log_vec(const vfloat4 xv,
                                            float& v0, float& v1, float& v2) {
    const float a = xv.x, b = xv.y, c = xv.w;
    const float m    = 0.5f * (a + c);
    const float h    = 0.5f * (a - c);
    const float disc = sqrtf(fmaf(h, h, b * b));
    const float lam1 = m + disc;
    const float det  = fmaf(a, c, -b * b);
    const float lam2 = __fdividef(det, lam1);
    const float l1 = __logf(lam1);
    const float l2 = __logf(lam2);
    const float p  = 0.5f * (l1 + l2);
    const float q  = 0.5f * (l1 - l2);
    const float rho = (disc > 1e-20f) ? __fdividef(q, disc)
                                      : __fdividef(1.0f, m);
    v0 = fmaf(rho, h, p);
    v1 = SQRT2F * rho * b;
    v2 = fmaf(-rho, h, p);
}

__global__ __launch_bounds__(256) void spd_direct_kernel(
    const vfloat4* __restrict__ x,     // [NMAT]
    const float*   __restrict__ W,     // [17*3]
    const float*   __restrict__ bias,  // [17]
    vfloat4*       __restrict__ out)   // [NMAT*17/4]
{
    __shared__ float sWb[17][4];       // {W[j][0..2], b[j]} per row, 16B each

    const int t = threadIdx.x;
    if (t < 68) {
        const int j = t >> 2, c = t & 3;
        sWb[j][c] = (c < 3) ? W[j * 3 + c] : bias[j];
    }
    __syncthreads();                   // only barrier; before bulk traffic

    const int g0 = blockIdx.x * 1024 + t;   // output float4 index base

    #pragma unroll
    for (int kk = 0; kk < 4; ++kk) {
        const int g  = g0 + kk * 256;
        const int f  = g * 4;               // first flat float index (< 2^26)
        const int r0 = f / 17;              // source matrix of float 0
        const int j0 = f - r0 * 17;         // its column in [0,17)
        const int r1 = (r0 + 1 < NMAT) ? r0 + 1 : r0;  // clamp (unused when j0<14)

        float a0, a1, a2, b0, b1, b2;
        mat_log_vec(x[r0], a0, a1, a2);
        mat_log_vec(x[r1], b0, b1, b2);     // branchless: every wave pays anyway

        vfloat4 o;
        #pragma unroll
        for (int k = 0; k < 4; ++k) {
            int j = j0 + k;
            const bool hi = (j >= 17);
            j -= hi ? 17 : 0;
            const float u0 = hi ? b0 : a0;
            const float u1 = hi ? b1 : a1;
            const float u2 = hi ? b2 : a2;
            const vfloat4 wb = *(const vfloat4*)&sWb[j][0];
            const float r = fmaf(u0, wb.x, fmaf(u1, wb.y, fmaf(u2, wb.z, wb.w)));
            if (k == 0) o.x = r; else if (k == 1) o.y = r;
            else if (k == 2) o.z = r; else o.w = r;
        }
        out[g] = o;
    }
}

extern "C" void kernel_launch(void* const* d_in, const int* in_sizes, int n_in,
                              void* d_out, int out_size, void* d_ws, size_t ws_size,
                              hipStream_t stream) {
    const float* x = (const float*)d_in[0];   // [B,2,2]
    const float* W = (const float*)d_in[1];   // [17,3]
    const float* b = (const float*)d_in[2];   // [17]
    float* out = (float*)d_out;               // [B,17]

    // out_size = 2097152*17 = 35651584 floats = 8912896 float4
    // threads: 256/block, 4 float4 each -> 8704 blocks exactly
    const int blocks = (out_size / 4) / 1024;

    spd_direct_kernel<<<blocks, 256, 0, stream>>>(
        (const vfloat4*)x, W, b, (vfloat4*)d_out);
}